// Round 20
// baseline (57.353 us; speedup 1.0000x reference)
//
#include <hip/hip_runtime.h>

// Multi-Scale Deformable Attention forward, fp32 in/out.
// B=1, Q=19947, heads=8, D=32, L=4, P=4.
// Levels: (100,150),(50,75),(25,38),(13,19); starts 0,15000,18750,19700.
//
// - Head-per-XCD: blockIdx.x%8 == head rides round-robin XCD dispatch;
//   fp16 paired-row slice (2.55 MB/XCD) L2-resident.
// - Paired rows, layout [g][slot][8ch]: row t = 128 B, slot s = token t+s.
//   One row read serves both bilinear x-corners (halves L2 line requests;
//   5.1M line-reads ~ 80% of random L2 ceiling).
// - Metadata once per (pair,sample) in LDS (R19 win), stride 12 words
//   (2-way bank aliasing = free) vs 8 (4-way, 3.35M conflicts in R19).
// - cvt builds a full row g-chunk per thread: 2 reads (L2-amplified,
//   cheap) + ONE contiguous 32 B store (R19's dual scattered 16 B
//   stores = 40.8 MB writes were ~12 us).
// - Rejected: R11 big-LDS meta, R12 shfl meta, R16 sw-pipeline, R17
//   pure TLP, R18 redundant-meta 16-lane (VALU wall).

typedef float    f32x2 __attribute__((ext_vector_type(2)));
typedef float    f32x4 __attribute__((ext_vector_type(4)));
typedef float    f32x8 __attribute__((ext_vector_type(8)));
typedef _Float16 f16x8 __attribute__((ext_vector_type(8)));

constexpr int HEADS = 8;
constexpr int DCH   = 32;
constexpr int NSP   = 16;
constexpr int NQ    = 19947;
constexpr int HSTR2 = NQ * 64;         // fp16 elems per head slice (paired rows)

// ---- cvt: fp32 [tok][head][ch] -> fp16 paired rows [h][t][g][slot][8ch] ----
// row t elem offset = g*16 + s*8 ; slot s = token t+s. One 32 B store/thread.
__global__ __launch_bounds__(256)
void cvt_pair_kernel(const float* __restrict__ value, _Float16* __restrict__ ws)
{
    const int h = blockIdx.x & 7;                       // head == XCD id
    const int i = (blockIdx.x >> 3) * 256 + threadIdx.x;
    if (i >= NQ * 4) return;
    const int g = i & 3;
    const int t = i >> 2;

    const float* s0 = value + (size_t)t * 256 + h * 32 + g * 8;
    const f32x4 a0 = __builtin_nontemporal_load((const f32x4*)s0);
    const f32x4 a1 = __builtin_nontemporal_load((const f32x4*)(s0 + 4));
    f32x4 b0 = {}, b1 = {};
    if (t + 1 < NQ) {
        const float* s1 = s0 + 256;
        b0 = *(const f32x4*)s1;          // L1/L2 hit (neighbor's line)
        b1 = *(const f32x4*)(s1 + 4);
    }
    const f32x8 va = {a0.x, a0.y, a0.z, a0.w, a1.x, a1.y, a1.z, a1.w};
    const f32x8 vb = {b0.x, b0.y, b0.z, b0.w, b1.x, b1.y, b1.z, b1.w};
    _Float16* dst = ws + (size_t)h * HSTR2 + (size_t)t * 64 + g * 16;
    *(f16x8*)dst       = __builtin_convertvector(va, f16x8);   // slot0
    *(f16x8*)(dst + 8) = __builtin_convertvector(vb, f16x8);   // slot1 (contig)
}

// ---- main kernel: phase-1 LDS metadata, phase-2 paired-row gather ----------
__global__ __launch_bounds__(256)
void msda_meta_kernel(const _Float16* __restrict__ ws,
                      const float* __restrict__ loc,
                      const float* __restrict__ attw,
                      float* __restrict__ out)
{
    constexpr int QPB  = 16;             // pairs per block (256 thr / 16 lanes)
    constexpr int SSTR = 12;             // words per sample (48 B, 16 B aligned)
    constexpr int PSTR = NSP * SSTR + 4; // 196 words: pairs on distinct bank quads
    __shared__ __align__(16) float s_meta[QPB][PSTR];   // 12.5 KB

    const int h    = blockIdx.x & 7;          // head == XCD id
    const int qblk = blockIdx.x >> 3;
    const int q0   = qblk * QPB;
    const int t    = threadIdx.x;

    // ---- phase 1: one metadata item per thread ----
    {
        const int pair = t >> 4, sp = t & 15;
        const int q = q0 + pair;
        if (q < NQ) {
            const size_t mb = (size_t)(q * HEADS + h);
            const f32x2 xy = __builtin_nontemporal_load(
                (const f32x2*)(loc + mb * (NSP * 2) + sp * 2));
            const float aw = __builtin_nontemporal_load(attw + mb * NSP + sp);

            const int l = sp >> 2;
            const float fW = (l == 0) ? 150.f : (l == 1) ? 75.f : (l == 2) ? 38.f : 19.f;
            const float fH = (l == 0) ? 100.f : (l == 1) ? 50.f : (l == 2) ? 25.f : 13.f;
            const int   W  = (l == 0) ? 150   : (l == 1) ? 75   : (l == 2) ? 38   : 19;
            const int   H  = (l == 0) ? 100   : (l == 1) ? 50   : (l == 2) ? 25   : 13;
            const int   S  = (l == 0) ? 0     : (l == 1) ? 15000: (l == 2) ? 18750: 19700;

            const float x = xy.x * fW - 0.5f;
            const float y = xy.y * fH - 0.5f;
            const float x0f = floorf(x);
            const float y0f = floorf(y);
            const float wx1 = x - x0f;
            const float wy1 = y - y0f;
            const float wx0 = 1.f - wx1;
            const float wy0 = 1.f - wy1;
            const int x0 = (int)x0f, y0 = (int)y0f;   // in [-1, W-1]
            const int x1 = x0 + 1,   y1 = y0 + 1;     // in [0, W]

            const float wx0m = ((unsigned)x0 < (unsigned)W) ? wx0 : 0.f;
            const float wx1m = ((unsigned)x1 < (unsigned)W) ? wx1 : 0.f;
            const float wy0m = ((unsigned)y0 < (unsigned)H) ? aw * wy0 : 0.f;
            const float wy1m = ((unsigned)y1 < (unsigned)H) ? aw * wy1 : 0.f;
            const float c00 = wy0m * wx0m;
            const float c01 = wy0m * wx1m;
            const float c10 = wy1m * wx0m;
            const float c11 = wy1m * wx1m;

            const int cx0 = max(x0, 0), cx1 = min(x1, W - 1);
            const int cy0 = max(y0, 0), cy1 = min(y1, H - 1);
            const bool xi = cx1 > cx0;     // slot1 really is corner x1

            // per-slot coefficients (x-clamp folded): m[s]=slot s y0, m[2+s]=slot s y1
            float* m = &s_meta[pair][sp * SSTR];
            m[0] = xi ? c00 : (c00 + c01);
            m[1] = xi ? c01 : 0.f;
            m[2] = xi ? c10 : (c10 + c11);
            m[3] = xi ? c11 : 0.f;
            int* mi = (int*)m;
            mi[4] = S + cy0 * W + cx0;     // row base y0
            mi[5] = S + cy1 * W + cx0;     // row base y1
        }
    }
    __syncthreads();

    // ---- phase 2: gather + accumulate ----
    const int pair = t >> 4;
    const int lane = t & 15;
    const int g    = lane & 3;            // ch group (8 ch)
    const int s    = (lane >> 2) & 1;     // token slot
    const int half = lane >> 3;           // sample half: 0 -> sp 0-7, 1 -> 8-15
    const int q    = q0 + pair;
    if (q >= NQ) return;

    const _Float16* vf = ws + (size_t)h * HSTR2 + g * 16 + s * 8;

    f32x8 acc = {0.f, 0.f, 0.f, 0.f, 0.f, 0.f, 0.f, 0.f};
    const int sp0 = half * 8;

#pragma unroll
    for (int u = 0; u < 8; ++u) {
        const float* m = &s_meta[pair][(sp0 + u) * SSTR];
        const float fA = m[s];                    // slot s, y-row 0
        const float fB = m[2 + s];                // slot s, y-row 1
        const int rb0 = ((const int*)m)[4];
        const int rb1 = ((const int*)m)[5];

        const f16x8 g0 = *(const f16x8*)(vf + (size_t)rb0 * 64);
        const f16x8 g1 = *(const f16x8*)(vf + (size_t)rb1 * 64);
#pragma unroll
        for (int k = 0; k < 8; ++k) {
            acc[k] += fA * (float)g0[k];
            acc[k] += fB * (float)g1[k];
        }
    }

    // combine slots (xor 4) then halves (xor 8)
#pragma unroll
    for (int k = 0; k < 8; ++k) acc[k] += __shfl_xor(acc[k], 4);
#pragma unroll
    for (int k = 0; k < 8; ++k) acc[k] += __shfl_xor(acc[k], 8);

    if (s == 0) {   // 8 lanes (half,g) x 16 B = contiguous 128 B per pair
        float* op = out + (size_t)(q * HEADS + h) * DCH + g * 8 + half * 4;
        const f32x4 part = half ? f32x4{acc[4], acc[5], acc[6], acc[7]}
                                : f32x4{acc[0], acc[1], acc[2], acc[3]};
        __builtin_nontemporal_store(part, (f32x4*)op);
    }
}

// ---- fp32 direct fallback (correctness only, tiny ws) ----------------------
__global__ __launch_bounds__(256)
void msda_f32_kernel(const float* __restrict__ value,
                     const float* __restrict__ loc,
                     const float* __restrict__ attw,
                     float* __restrict__ out)
{
    const int t    = blockIdx.x * blockDim.x + threadIdx.x;
    const int pair = t >> 3;
    const int d0   = (t & 7) * 4;
    if (pair >= NQ * HEADS) return;
    const int h = pair & 7;

    const float* locp = loc  + (size_t)pair * (NSP * 2);
    const float* awp  = attw + (size_t)pair * NSP;
    f32x4 acc = {0.f, 0.f, 0.f, 0.f};

#pragma unroll
    for (int sp = 0; sp < NSP; ++sp) {
        const int l = sp >> 2;
        const int W = (l == 0) ? 150 : (l == 1) ? 75 : (l == 2) ? 38 : 19;
        const int H = (l == 0) ? 100 : (l == 1) ? 50 : (l == 2) ? 25 : 13;
        const int S = (l == 0) ? 0 : (l == 1) ? 15000 : (l == 2) ? 18750 : 19700;
        const float x = locp[sp * 2] * W - 0.5f;
        const float y = locp[sp * 2 + 1] * H - 0.5f;
        const float aw = awp[sp];
        const float x0f = floorf(x), y0f = floorf(y);
        const float wx1 = x - x0f, wy1 = y - y0f;
        const float wx0 = 1.f - wx1, wy0 = 1.f - wy1;
        const int x0 = (int)x0f, y0 = (int)y0f, x1 = x0 + 1, y1 = y0 + 1;
        const float wx0m = ((unsigned)x0 < (unsigned)W) ? wx0 : 0.f;
        const float wx1m = ((unsigned)x1 < (unsigned)W) ? wx1 : 0.f;
        const float wy0m = ((unsigned)y0 < (unsigned)H) ? aw * wy0 : 0.f;
        const float wy1m = ((unsigned)y1 < (unsigned)H) ? aw * wy1 : 0.f;
        const int cx0 = max(x0, 0), cx1 = min(x1, W - 1);
        const int cy0 = max(y0, 0), cy1 = min(y1, H - 1);
        const size_t r0 = (size_t)(S + cy0 * W), r1 = (size_t)(S + cy1 * W);
        const f32x4 g00 = *(const f32x4*)(value + ((r0 + cx0) * 8 + h) * DCH + d0);
        const f32x4 g01 = *(const f32x4*)(value + ((r0 + cx1) * 8 + h) * DCH + d0);
        const f32x4 g10 = *(const f32x4*)(value + ((r1 + cx0) * 8 + h) * DCH + d0);
        const f32x4 g11 = *(const f32x4*)(value + ((r1 + cx1) * 8 + h) * DCH + d0);
        acc += g00 * (wy0m * wx0m);
        acc += g01 * (wy0m * wx1m);
        acc += g10 * (wy1m * wx0m);
        acc += g11 * (wy1m * wx1m);
    }
    *(f32x4*)(out + (size_t)pair * DCH + d0) = acc;
}

extern "C" void kernel_launch(void* const* d_in, const int* in_sizes, int n_in,
                              void* d_out, int out_size, void* d_ws, size_t ws_size,
                              hipStream_t stream) {
    const float* value = (const float*)d_in[0];
    const float* loc   = (const float*)d_in[3];
    const float* attw  = (const float*)d_in[4];
    float* out = (float*)d_out;

    const size_t pair_bytes = (size_t)NQ * HEADS * 64 * sizeof(_Float16); // 20.4 MB

    if (ws_size >= pair_bytes) {
        _Float16* ws = (_Float16*)d_ws;
        const int cgrid = ((NQ * 4 + 255) / 256) * HEADS;                 // XCD-aligned
        cvt_pair_kernel<<<cgrid, 256, 0, stream>>>(value, ws);
        const int qblocks = (NQ + 15) / 16;                               // 1247
        msda_meta_kernel<<<qblocks * HEADS, 256, 0, stream>>>(ws, loc, attw, out);
    } else {
        const int total = NQ * HEADS * 8;
        msda_f32_kernel<<<(total + 255) / 256, 256, 0, stream>>>(value, loc, attw, out);
    }
}

// Round 21
// 56.700 us; speedup vs baseline: 1.0115x; 1.0115x over previous
//
#include <hip/hip_runtime.h>

// Multi-Scale Deformable Attention forward, fp32 in/out.
// B=1, Q=19947, heads=8, D=32, L=4, P=4.
// Levels: (100,150),(50,75),(25,38),(13,19); starts 0,15000,18750,19700.
//
// - Head-per-XCD: blockIdx.x%8 == head rides round-robin XCD dispatch;
//   flat fp16 head-major slice [h][tok][32ch] (1.28 MB/XCD) L2-resident.
// - R21 insight: flat layout ALREADY has x-corner pairs contiguous --
//   tokens rb,rb+1 = adjacent 64 B blocks. 16 lanes/pair (half,s,g):
//   8 lanes read one dense 128 B line per y-row (same request count as
//   the paired layout, R18-R20) with ZERO duplication -> cvt is the
//   cheap 10.2 MB R17 version (~7 us vs 12-15 us), the R20 sink.
// - Metadata once per (pair,sample) in 12.5 KB LDS (R19 win), per-slot
//   x-clamp folded coefficients; slot-1 edge overflow reads x0-garbage
//   with coeff 0 (never NaN: 0xAA poison = normal fp16).
// - Rejected: R11 big-LDS meta, R12 shfl meta, R16 sw-pipeline, R17
//   pure TLP, R18 redundant-meta (VALU wall), R20 paired-duplicate cvt.

typedef float    f32x2 __attribute__((ext_vector_type(2)));
typedef float    f32x4 __attribute__((ext_vector_type(4)));
typedef float    f32x8 __attribute__((ext_vector_type(8)));
typedef _Float16 f16x8 __attribute__((ext_vector_type(8)));

constexpr int HEADS = 8;
constexpr int DCH   = 32;
constexpr int NSP   = 16;
constexpr int NQ    = 19947;
constexpr int HSTR  = NQ * DCH;        // fp16 elems per head slice (flat)
constexpr int NVAL  = NQ * HEADS * DCH;

// ---- cvt: fp32 [tok][head][ch] -> fp16 head-major [h][tok][32ch] -----------
__global__ __launch_bounds__(256)
void cvt_kernel(const float* __restrict__ value, _Float16* __restrict__ ws)
{
    const int h = blockIdx.x & 7;                       // head == XCD id
    const int i = (blockIdx.x >> 3) * 256 + threadIdx.x;
    if (i >= NQ * 4) return;
    const int g   = i & 3;
    const int tok = i >> 2;
    const float* src = value + (size_t)tok * 256 + h * 32 + g * 8;
    const f32x4 a = __builtin_nontemporal_load((const f32x4*)src);
    const f32x4 b = __builtin_nontemporal_load((const f32x4*)(src + 4));
    const f32x8 v = {a.x, a.y, a.z, a.w, b.x, b.y, b.z, b.w};
    *(f16x8*)(ws + (size_t)h * HSTR + (size_t)tok * 32 + g * 8) =
        __builtin_convertvector(v, f16x8);              // stays in XCD L2
}

// ---- main kernel: phase-1 LDS metadata, phase-2 flat-line gather -----------
__global__ __launch_bounds__(256)
void msda_meta_kernel(const _Float16* __restrict__ ws,
                      const float* __restrict__ loc,
                      const float* __restrict__ attw,
                      float* __restrict__ out)
{
    constexpr int QPB  = 16;             // pairs per block (256 thr / 16 lanes)
    constexpr int SSTR = 12;             // words per sample (48 B, 16 B aligned)
    constexpr int PSTR = NSP * SSTR + 4; // 196 words
    __shared__ __align__(16) float s_meta[QPB][PSTR];   // 12.5 KB

    const int h    = blockIdx.x & 7;          // head == XCD id
    const int qblk = blockIdx.x >> 3;
    const int q0   = qblk * QPB;
    const int t    = threadIdx.x;

    // ---- phase 1: one metadata item per thread ----
    {
        const int pair = t >> 4, sp = t & 15;
        const int q = q0 + pair;
        if (q < NQ) {
            const size_t mb = (size_t)(q * HEADS + h);
            const f32x2 xy = __builtin_nontemporal_load(
                (const f32x2*)(loc + mb * (NSP * 2) + sp * 2));
            const float aw = __builtin_nontemporal_load(attw + mb * NSP + sp);

            const int l = sp >> 2;
            const float fW = (l == 0) ? 150.f : (l == 1) ? 75.f : (l == 2) ? 38.f : 19.f;
            const float fH = (l == 0) ? 100.f : (l == 1) ? 50.f : (l == 2) ? 25.f : 13.f;
            const int   W  = (l == 0) ? 150   : (l == 1) ? 75   : (l == 2) ? 38   : 19;
            const int   H  = (l == 0) ? 100   : (l == 1) ? 50   : (l == 2) ? 25   : 13;
            const int   S  = (l == 0) ? 0     : (l == 1) ? 15000: (l == 2) ? 18750: 19700;

            const float x = xy.x * fW - 0.5f;
            const float y = xy.y * fH - 0.5f;
            const float x0f = floorf(x);
            const float y0f = floorf(y);
            const float wx1 = x - x0f;
            const float wy1 = y - y0f;
            const float wx0 = 1.f - wx1;
            const float wy0 = 1.f - wy1;
            const int x0 = (int)x0f, y0 = (int)y0f;   // in [-1, W-1]
            const int x1 = x0 + 1,   y1 = y0 + 1;     // in [0, W]

            const float wx0m = ((unsigned)x0 < (unsigned)W) ? wx0 : 0.f;
            const float wx1m = ((unsigned)x1 < (unsigned)W) ? wx1 : 0.f;
            const float wy0m = ((unsigned)y0 < (unsigned)H) ? aw * wy0 : 0.f;
            const float wy1m = ((unsigned)y1 < (unsigned)H) ? aw * wy1 : 0.f;
            const float c00 = wy0m * wx0m;
            const float c01 = wy0m * wx1m;
            const float c10 = wy1m * wx0m;
            const float c11 = wy1m * wx1m;

            const int cx0 = max(x0, 0), cx1 = min(x1, W - 1);
            const int cy0 = max(y0, 0), cy1 = min(y1, H - 1);
            const bool xi = cx1 > cx0;     // slot1 really is corner x1

            // per-slot coefficients (x-clamp folded): m[s]=slot s y0, m[2+s]=slot s y1
            float* m = &s_meta[pair][sp * SSTR];
            m[0] = xi ? c00 : (c00 + c01);
            m[1] = xi ? c01 : 0.f;
            m[2] = xi ? c10 : (c10 + c11);
            m[3] = xi ? c11 : 0.f;
            int* mi = (int*)m;
            mi[4] = S + cy0 * W + cx0;     // token base y0 (slot s = +s)
            mi[5] = S + cy1 * W + cx0;     // token base y1
        }
    }
    __syncthreads();

    // ---- phase 2: gather + accumulate (flat layout, dense 128 B lines) ----
    const int pair = t >> 4;
    const int lane = t & 15;
    const int g    = lane & 3;            // ch group (8 ch)
    const int s    = (lane >> 2) & 1;     // token slot (x corner)
    const int half = lane >> 3;           // sample half: 0 -> sp 0-7, 1 -> 8-15
    const int q    = q0 + pair;
    if (q >= NQ) return;

    // lane reads token rb+s, channels g*8..g*8+7:
    // elem = h*HSTR + (rb+s)*32 + g*8  ->  8 lanes cover rb*64B .. rb*64B+127B
    const _Float16* vf = ws + (size_t)h * HSTR + s * 32 + g * 8;

    f32x8 acc = {0.f, 0.f, 0.f, 0.f, 0.f, 0.f, 0.f, 0.f};
    const int sp0 = half * 8;

#pragma unroll
    for (int u = 0; u < 8; ++u) {
        const float* m = &s_meta[pair][(sp0 + u) * SSTR];
        const float fA = m[s];                    // slot s, y-row 0
        const float fB = m[2 + s];                // slot s, y-row 1
        const int rb0 = ((const int*)m)[4];
        const int rb1 = ((const int*)m)[5];

        const f16x8 g0 = *(const f16x8*)(vf + (size_t)rb0 * 32);
        const f16x8 g1 = *(const f16x8*)(vf + (size_t)rb1 * 32);
#pragma unroll
        for (int k = 0; k < 8; ++k) {
            acc[k] += fA * (float)g0[k];
            acc[k] += fB * (float)g1[k];
        }
    }

    // combine slots (xor 4) then halves (xor 8)
#pragma unroll
    for (int k = 0; k < 8; ++k) acc[k] += __shfl_xor(acc[k], 4);
#pragma unroll
    for (int k = 0; k < 8; ++k) acc[k] += __shfl_xor(acc[k], 8);

    if (s == 0) {   // 8 lanes (half,g) x 16 B = contiguous 128 B per pair
        float* op = out + (size_t)(q * HEADS + h) * DCH + g * 8 + half * 4;
        const f32x4 part = half ? f32x4{acc[4], acc[5], acc[6], acc[7]}
                                : f32x4{acc[0], acc[1], acc[2], acc[3]};
        __builtin_nontemporal_store(part, (f32x4*)op);
    }
}

// ---- fp32 direct fallback (correctness only, tiny ws) ----------------------
__global__ __launch_bounds__(256)
void msda_f32_kernel(const float* __restrict__ value,
                     const float* __restrict__ loc,
                     const float* __restrict__ attw,
                     float* __restrict__ out)
{
    const int t    = blockIdx.x * blockDim.x + threadIdx.x;
    const int pair = t >> 3;
    const int d0   = (t & 7) * 4;
    if (pair >= NQ * HEADS) return;
    const int h = pair & 7;

    const float* locp = loc  + (size_t)pair * (NSP * 2);
    const float* awp  = attw + (size_t)pair * NSP;
    f32x4 acc = {0.f, 0.f, 0.f, 0.f};

#pragma unroll
    for (int sp = 0; sp < NSP; ++sp) {
        const int l = sp >> 2;
        const int W = (l == 0) ? 150 : (l == 1) ? 75 : (l == 2) ? 38 : 19;
        const int H = (l == 0) ? 100 : (l == 1) ? 50 : (l == 2) ? 25 : 13;
        const int S = (l == 0) ? 0 : (l == 1) ? 15000 : (l == 2) ? 18750 : 19700;
        const float x = locp[sp * 2] * W - 0.5f;
        const float y = locp[sp * 2 + 1] * H - 0.5f;
        const float aw = awp[sp];
        const float x0f = floorf(x), y0f = floorf(y);
        const float wx1 = x - x0f, wy1 = y - y0f;
        const float wx0 = 1.f - wx1, wy0 = 1.f - wy1;
        const int x0 = (int)x0f, y0 = (int)y0f, x1 = x0 + 1, y1 = y0 + 1;
        const float wx0m = ((unsigned)x0 < (unsigned)W) ? wx0 : 0.f;
        const float wx1m = ((unsigned)x1 < (unsigned)W) ? wx1 : 0.f;
        const float wy0m = ((unsigned)y0 < (unsigned)H) ? aw * wy0 : 0.f;
        const float wy1m = ((unsigned)y1 < (unsigned)H) ? aw * wy1 : 0.f;
        const int cx0 = max(x0, 0), cx1 = min(x1, W - 1);
        const int cy0 = max(y0, 0), cy1 = min(y1, H - 1);
        const size_t r0 = (size_t)(S + cy0 * W), r1 = (size_t)(S + cy1 * W);
        const f32x4 g00 = *(const f32x4*)(value + ((r0 + cx0) * 8 + h) * DCH + d0);
        const f32x4 g01 = *(const f32x4*)(value + ((r0 + cx1) * 8 + h) * DCH + d0);
        const f32x4 g10 = *(const f32x4*)(value + ((r1 + cx0) * 8 + h) * DCH + d0);
        const f32x4 g11 = *(const f32x4*)(value + ((r1 + cx1) * 8 + h) * DCH + d0);
        acc += g00 * (wy0m * wx0m);
        acc += g01 * (wy0m * wx1m);
        acc += g10 * (wy1m * wx0m);
        acc += g11 * (wy1m * wx1m);
    }
    *(f32x4*)(out + (size_t)pair * DCH + d0) = acc;
}

extern "C" void kernel_launch(void* const* d_in, const int* in_sizes, int n_in,
                              void* d_out, int out_size, void* d_ws, size_t ws_size,
                              hipStream_t stream) {
    const float* value = (const float*)d_in[0];
    const float* loc   = (const float*)d_in[3];
    const float* attw  = (const float*)d_in[4];
    float* out = (float*)d_out;

    const size_t f16_bytes = (size_t)NVAL * sizeof(_Float16) + 256;  // +edge pad

    if (ws_size >= f16_bytes) {
        _Float16* ws = (_Float16*)d_ws;
        const int cgrid = ((NQ * 4 + 255) / 256) * HEADS;            // XCD-aligned
        cvt_kernel<<<cgrid, 256, 0, stream>>>(value, ws);
        const int qblocks = (NQ + 15) / 16;                          // 1247
        msda_meta_kernel<<<qblocks * HEADS, 256, 0, stream>>>(ws, loc, attw, out);
    } else {
        const int total = NQ * HEADS * 8;
        msda_f32_kernel<<<(total + 255) / 256, 256, 0, stream>>>(value, loc, attw, out);
    }
}

// Round 22
// 53.203 us; speedup vs baseline: 1.0780x; 1.0657x over previous
//
#include <hip/hip_runtime.h>

// Multi-Scale Deformable Attention forward, fp32 in/out.
// B=1, Q=19947, heads=8, D=32, L=4, P=4.
// Levels: (100,150),(50,75),(25,38),(13,19); starts 0,15000,18750,19700.
//
// - Head-per-XCD: blockIdx.x%8 == head rides round-robin XCD dispatch;
//   fp16 paired-row slice (2.55 MB/XCD) L2-resident.
// - Paired rows [t][g][slot][8ch]: row t = 128 B holds tokens {t,t+1};
//   one dense line serves both bilinear x-corners (2 lines/sample,
//   proven best gather: 41.5 us R20 vs 47.8 flat R21).
// - R22: LDS metadata as 16 B entries {coefY0,coefY1,rb0,rb1} per
//   (pair,sample,slot). Phase 2 preloads each lane's 8 entries via
//   ds_read_b128 at immediate offsets into REGISTERS before the gather
//   loop -> corner loads have zero LDS dependency, deep vmem pipeline
//   (R16's MLP attempt failed because meta stayed LDS-resident).
// - Rejected: R11/R12 dedup-by-communication, R16 sw-pipeline (LDS dep),
//   R17 pure TLP, R18 redundant-meta (VALU wall), R21 flat rows (1.5x
//   lines), R20 read-amplified cvt.

typedef float    f32x2 __attribute__((ext_vector_type(2)));
typedef float    f32x4 __attribute__((ext_vector_type(4)));
typedef float    f32x8 __attribute__((ext_vector_type(8)));
typedef _Float16 f16x8 __attribute__((ext_vector_type(8)));

constexpr int HEADS = 8;
constexpr int DCH   = 32;
constexpr int NSP   = 16;
constexpr int NQ    = 19947;
constexpr int HSTR2 = NQ * 64;         // fp16 elems per head slice (paired rows)

// ---- cvt: fp32 [tok][head][ch] -> fp16 paired rows [h][t][g][slot][8ch] ----
// row t elem offset = g*16 + s*8 ; slot s = token t+s. (R19 shape, ~12 us)
__global__ __launch_bounds__(256)
void cvt_pair_kernel(const float* __restrict__ value, _Float16* __restrict__ ws)
{
    const int h = blockIdx.x & 7;                       // head == XCD id
    const int i = (blockIdx.x >> 3) * 256 + threadIdx.x;
    if (i >= NQ * 4) return;
    const int g = i & 3;
    const int t = i >> 2;
    const float* src = value + (size_t)t * 256 + h * 32 + g * 8;
    const f32x4 a = __builtin_nontemporal_load((const f32x4*)src);
    const f32x4 b = __builtin_nontemporal_load((const f32x4*)(src + 4));
    const f32x8 v = {a.x, a.y, a.z, a.w, b.x, b.y, b.z, b.w};
    const f16x8 o = __builtin_convertvector(v, f16x8);
    _Float16* base = ws + (size_t)h * HSTR2;
    *(f16x8*)(base + (size_t)t * 64 + g * 16) = o;                  // row t slot0
    if (t > 0)
        *(f16x8*)(base + (size_t)(t - 1) * 64 + g * 16 + 8) = o;    // row t-1 slot1
    if (t == NQ - 1) {
        const f16x8 z = {};
        *(f16x8*)(base + (size_t)t * 64 + g * 16 + 8) = z;          // pad slot
    }
}

// ---- main kernel ------------------------------------------------------------
__global__ __launch_bounds__(256)
void msda_meta_kernel(const _Float16* __restrict__ ws,
                      const float* __restrict__ loc,
                      const float* __restrict__ attw,
                      float* __restrict__ out)
{
    constexpr int QPB  = 16;             // pairs per block (256 thr / 16 lanes)
    constexpr int PSTR = 132;            // words per pair (528 B, 16 B aligned)
    __shared__ __align__(16) float s_meta[QPB * PSTR];  // 8.25 KB

    const int h    = blockIdx.x & 7;          // head == XCD id
    const int qblk = blockIdx.x >> 3;
    const int q0   = qblk * QPB;
    const int t    = threadIdx.x;

    // ---- phase 1: one metadata item per thread, two 16 B slot entries ----
    {
        const int pair = t >> 4, sp = t & 15;
        const int q = q0 + pair;
        if (q < NQ) {
            const size_t mb = (size_t)(q * HEADS + h);
            const f32x2 xy = __builtin_nontemporal_load(
                (const f32x2*)(loc + mb * (NSP * 2) + sp * 2));
            const float aw = __builtin_nontemporal_load(attw + mb * NSP + sp);

            const int l = sp >> 2;
            const float fW = (l == 0) ? 150.f : (l == 1) ? 75.f : (l == 2) ? 38.f : 19.f;
            const float fH = (l == 0) ? 100.f : (l == 1) ? 50.f : (l == 2) ? 25.f : 13.f;
            const int   W  = (l == 0) ? 150   : (l == 1) ? 75   : (l == 2) ? 38   : 19;
            const int   H  = (l == 0) ? 100   : (l == 1) ? 50   : (l == 2) ? 25   : 13;
            const int   S  = (l == 0) ? 0     : (l == 1) ? 15000: (l == 2) ? 18750: 19700;

            const float x = xy.x * fW - 0.5f;
            const float y = xy.y * fH - 0.5f;
            const float x0f = floorf(x);
            const float y0f = floorf(y);
            const float wx1 = x - x0f;
            const float wy1 = y - y0f;
            const float wx0 = 1.f - wx1;
            const float wy0 = 1.f - wy1;
            const int x0 = (int)x0f, y0 = (int)y0f;   // in [-1, W-1]
            const int x1 = x0 + 1,   y1 = y0 + 1;     // in [0, W]

            const float wx0m = ((unsigned)x0 < (unsigned)W) ? wx0 : 0.f;
            const float wx1m = ((unsigned)x1 < (unsigned)W) ? wx1 : 0.f;
            const float wy0m = ((unsigned)y0 < (unsigned)H) ? aw * wy0 : 0.f;
            const float wy1m = ((unsigned)y1 < (unsigned)H) ? aw * wy1 : 0.f;
            const float c00 = wy0m * wx0m;
            const float c01 = wy0m * wx1m;
            const float c10 = wy1m * wx0m;
            const float c11 = wy1m * wx1m;

            const int cx0 = max(x0, 0), cx1 = min(x1, W - 1);
            const int cy0 = max(y0, 0), cy1 = min(y1, H - 1);
            const bool xi = cx1 > cx0;     // slot1 really is corner x1
            const int rb0 = S + cy0 * W + cx0;   // paired row index, y0
            const int rb1 = S + cy1 * W + cx0;   // paired row index, y1

            float* m = &s_meta[pair * PSTR + sp * 8];
            f32x4 e0, e1;
            e0.x = xi ? c00 : (c00 + c01);
            e0.y = xi ? c10 : (c10 + c11);
            e0.z = __int_as_float(rb0);
            e0.w = __int_as_float(rb1);
            e1.x = xi ? c01 : 0.f;
            e1.y = xi ? c11 : 0.f;
            e1.z = __int_as_float(rb0);
            e1.w = __int_as_float(rb1);
            *(f32x4*)(m)     = e0;         // slot 0 entry
            *(f32x4*)(m + 4) = e1;         // slot 1 entry
        }
    }
    __syncthreads();

    // ---- phase 2: preload meta entries to registers, then pure gather ----
    const int pair = t >> 4;
    const int lane = t & 15;
    const int g    = lane & 3;            // ch group (8 ch)
    const int s    = (lane >> 2) & 1;     // token slot (x corner)
    const int half = lane >> 3;           // sample half: 0 -> sp 0-7, 1 -> 8-15
    const int q    = q0 + pair;
    if (q >= NQ) return;

    // lane's entry for sample sp0+u lives at base + u*32 B (immediate offsets)
    const float* mbase = &s_meta[pair * PSTR + (half * 8) * 8 + s * 4];
    f32x4 e0 = *(const f32x4*)(mbase + 0 * 8);
    f32x4 e1 = *(const f32x4*)(mbase + 1 * 8);
    f32x4 e2 = *(const f32x4*)(mbase + 2 * 8);
    f32x4 e3 = *(const f32x4*)(mbase + 3 * 8);
    f32x4 e4 = *(const f32x4*)(mbase + 4 * 8);
    f32x4 e5 = *(const f32x4*)(mbase + 5 * 8);
    f32x4 e6 = *(const f32x4*)(mbase + 6 * 8);
    f32x4 e7 = *(const f32x4*)(mbase + 7 * 8);

    const _Float16* vf = ws + (size_t)h * HSTR2 + g * 16 + s * 8;

    f32x8 acc = {0.f, 0.f, 0.f, 0.f, 0.f, 0.f, 0.f, 0.f};

#define SAMPLE(E)                                                         \
    {                                                                     \
        const int rb0 = __float_as_int(E.z);                              \
        const int rb1 = __float_as_int(E.w);                              \
        const f16x8 ga = *(const f16x8*)(vf + (size_t)rb0 * 64);          \
        const f16x8 gb = *(const f16x8*)(vf + (size_t)rb1 * 64);          \
        _Pragma("unroll")                                                 \
        for (int k = 0; k < 8; ++k) {                                     \
            acc[k] += E.x * (float)ga[k];                                 \
            acc[k] += E.y * (float)gb[k];                                 \
        }                                                                 \
    }
    SAMPLE(e0) SAMPLE(e1) SAMPLE(e2) SAMPLE(e3)
    SAMPLE(e4) SAMPLE(e5) SAMPLE(e6) SAMPLE(e7)
#undef SAMPLE

    // combine slots (xor 4) then halves (xor 8)
#pragma unroll
    for (int k = 0; k < 8; ++k) acc[k] += __shfl_xor(acc[k], 4);
#pragma unroll
    for (int k = 0; k < 8; ++k) acc[k] += __shfl_xor(acc[k], 8);

    if (s == 0) {   // 8 lanes (half,g) x 16 B = contiguous 128 B per pair
        float* op = out + (size_t)(q * HEADS + h) * DCH + g * 8 + half * 4;
        const f32x4 part = half ? f32x4{acc[4], acc[5], acc[6], acc[7]}
                                : f32x4{acc[0], acc[1], acc[2], acc[3]};
        __builtin_nontemporal_store(part, (f32x4*)op);
    }
}

// ---- fp32 direct fallback (correctness only, tiny ws) ----------------------
__global__ __launch_bounds__(256)
void msda_f32_kernel(const float* __restrict__ value,
                     const float* __restrict__ loc,
                     const float* __restrict__ attw,
                     float* __restrict__ out)
{
    const int t    = blockIdx.x * blockDim.x + threadIdx.x;
    const int pair = t >> 3;
    const int d0   = (t & 7) * 4;
    if (pair >= NQ * HEADS) return;
    const int h = pair & 7;

    const float* locp = loc  + (size_t)pair * (NSP * 2);
    const float* awp  = attw + (size_t)pair * NSP;
    f32x4 acc = {0.f, 0.f, 0.f, 0.f};

#pragma unroll
    for (int sp = 0; sp < NSP; ++sp) {
        const int l = sp >> 2;
        const int W = (l == 0) ? 150 : (l == 1) ? 75 : (l == 2) ? 38 : 19;
        const int H = (l == 0) ? 100 : (l == 1) ? 50 : (l == 2) ? 25 : 13;
        const int S = (l == 0) ? 0 : (l == 1) ? 15000 : (l == 2) ? 18750 : 19700;
        const float x = locp[sp * 2] * W - 0.5f;
        const float y = locp[sp * 2 + 1] * H - 0.5f;
        const float aw = awp[sp];
        const float x0f = floorf(x), y0f = floorf(y);
        const float wx1 = x - x0f, wy1 = y - y0f;
        const float wx0 = 1.f - wx1, wy0 = 1.f - wy1;
        const int x0 = (int)x0f, y0 = (int)y0f, x1 = x0 + 1, y1 = y0 + 1;
        const float wx0m = ((unsigned)x0 < (unsigned)W) ? wx0 : 0.f;
        const float wx1m = ((unsigned)x1 < (unsigned)W) ? wx1 : 0.f;
        const float wy0m = ((unsigned)y0 < (unsigned)H) ? aw * wy0 : 0.f;
        const float wy1m = ((unsigned)y1 < (unsigned)H) ? aw * wy1 : 0.f;
        const int cx0 = max(x0, 0), cx1 = min(x1, W - 1);
        const int cy0 = max(y0, 0), cy1 = min(y1, H - 1);
        const size_t r0 = (size_t)(S + cy0 * W), r1 = (size_t)(S + cy1 * W);
        const f32x4 g00 = *(const f32x4*)(value + ((r0 + cx0) * 8 + h) * DCH + d0);
        const f32x4 g01 = *(const f32x4*)(value + ((r0 + cx1) * 8 + h) * DCH + d0);
        const f32x4 g10 = *(const f32x4*)(value + ((r1 + cx0) * 8 + h) * DCH + d0);
        const f32x4 g11 = *(const f32x4*)(value + ((r1 + cx1) * 8 + h) * DCH + d0);
        acc += g00 * (wy0m * wx0m);
        acc += g01 * (wy0m * wx1m);
        acc += g10 * (wy1m * wx0m);
        acc += g11 * (wy1m * wx1m);
    }
    *(f32x4*)(out + (size_t)pair * DCH + d0) = acc;
}

extern "C" void kernel_launch(void* const* d_in, const int* in_sizes, int n_in,
                              void* d_out, int out_size, void* d_ws, size_t ws_size,
                              hipStream_t stream) {
    const float* value = (const float*)d_in[0];
    const float* loc   = (const float*)d_in[3];
    const float* attw  = (const float*)d_in[4];
    float* out = (float*)d_out;

    const size_t pair_bytes = (size_t)NQ * HEADS * 64 * sizeof(_Float16); // 20.4 MB

    if (ws_size >= pair_bytes) {
        _Float16* ws = (_Float16*)d_ws;
        const int cgrid = ((NQ * 4 + 255) / 256) * HEADS;                 // XCD-aligned
        cvt_pair_kernel<<<cgrid, 256, 0, stream>>>(value, ws);
        const int qblocks = (NQ + 15) / 16;                               // 1247
        msda_meta_kernel<<<qblocks * HEADS, 256, 0, stream>>>(ws, loc, attw, out);
    } else {
        const int total = NQ * HEADS * 8;
        msda_f32_kernel<<<(total + 255) / 256, 256, 0, stream>>>(value, loc, attw, out);
    }
}

// Round 23
// 53.149 us; speedup vs baseline: 1.0791x; 1.0010x over previous
//
#include <hip/hip_runtime.h>

// Multi-Scale Deformable Attention forward, fp32 in/out.
// B=1, Q=19947, heads=8, D=32, L=4, P=4.
// Levels: (100,150),(50,75),(25,38),(13,19); starts 0,15000,18750,19700.
//
// - Head-per-XCD: blockIdx.x%8 == head rides round-robin XCD dispatch;
//   fp16 paired-row slice (2.55 MB/XCD) L2-resident.
// - Paired rows [t][g][slot][8ch]: row t = 128 B holds tokens {t,t+1};
//   one dense line serves both bilinear x-corners (best gather 41.4 us).
// - LDS metadata once per (pair,sample): 16 B entries {cY0,cY1,rb0,rb1}
//   per slot (R19/R22 win).
// - R23: LOAD-ALL-THEN-COMPUTE. Phase 2a issues all 16 corner loads
//   into explicit f16x8 arrays (no FMAs interleaved -> compiler cannot
//   sink loads; 16 outstanding vmem/wave, ~64/CU vs ~15). Phase 2b does
//   the FMA pass re-reading coefs from LDS while loads are in flight.
//   VGPR is the tell: ~32 = collapsed again, ~120 = materialized.
// - Rejected: R11/R12 dedup-by-comm, R16/R22 compiler-invisible
//   pipelining, R17 pure TLP, R18 redundant-meta, R21 flat rows.

typedef float    f32x2 __attribute__((ext_vector_type(2)));
typedef float    f32x4 __attribute__((ext_vector_type(4)));
typedef float    f32x8 __attribute__((ext_vector_type(8)));
typedef _Float16 f16x8 __attribute__((ext_vector_type(8)));

constexpr int HEADS = 8;
constexpr int DCH   = 32;
constexpr int NSP   = 16;
constexpr int NQ    = 19947;
constexpr int HSTR2 = NQ * 64;         // fp16 elems per head slice (paired rows)

// ---- cvt: fp32 [tok][head][ch] -> fp16 paired rows [h][t][g][slot][8ch] ----
__global__ __launch_bounds__(256)
void cvt_pair_kernel(const float* __restrict__ value, _Float16* __restrict__ ws)
{
    const int h = blockIdx.x & 7;                       // head == XCD id
    const int i = (blockIdx.x >> 3) * 256 + threadIdx.x;
    if (i >= NQ * 4) return;
    const int g = i & 3;
    const int t = i >> 2;
    const float* src = value + (size_t)t * 256 + h * 32 + g * 8;
    const f32x4 a = __builtin_nontemporal_load((const f32x4*)src);
    const f32x4 b = __builtin_nontemporal_load((const f32x4*)(src + 4));
    const f32x8 v = {a.x, a.y, a.z, a.w, b.x, b.y, b.z, b.w};
    const f16x8 o = __builtin_convertvector(v, f16x8);
    _Float16* base = ws + (size_t)h * HSTR2;
    *(f16x8*)(base + (size_t)t * 64 + g * 16) = o;                  // row t slot0
    if (t > 0)
        *(f16x8*)(base + (size_t)(t - 1) * 64 + g * 16 + 8) = o;    // row t-1 slot1
    if (t == NQ - 1) {
        const f16x8 z = {};
        *(f16x8*)(base + (size_t)t * 64 + g * 16 + 8) = z;          // pad slot
    }
}

// ---- main kernel ------------------------------------------------------------
__global__ __launch_bounds__(256)
void msda_meta_kernel(const _Float16* __restrict__ ws,
                      const float* __restrict__ loc,
                      const float* __restrict__ attw,
                      float* __restrict__ out)
{
    constexpr int QPB  = 16;             // pairs per block (256 thr / 16 lanes)
    constexpr int PSTR = 132;            // words per pair (528 B, 16 B aligned)
    __shared__ __align__(16) float s_meta[QPB * PSTR];  // 8.25 KB

    const int h    = blockIdx.x & 7;          // head == XCD id
    const int qblk = blockIdx.x >> 3;
    const int q0   = qblk * QPB;
    const int t    = threadIdx.x;

    // ---- phase 1: one metadata item per thread, two 16 B slot entries ----
    {
        const int pair = t >> 4, sp = t & 15;
        const int q = q0 + pair;
        if (q < NQ) {
            const size_t mb = (size_t)(q * HEADS + h);
            const f32x2 xy = __builtin_nontemporal_load(
                (const f32x2*)(loc + mb * (NSP * 2) + sp * 2));
            const float aw = __builtin_nontemporal_load(attw + mb * NSP + sp);

            const int l = sp >> 2;
            const float fW = (l == 0) ? 150.f : (l == 1) ? 75.f : (l == 2) ? 38.f : 19.f;
            const float fH = (l == 0) ? 100.f : (l == 1) ? 50.f : (l == 2) ? 25.f : 13.f;
            const int   W  = (l == 0) ? 150   : (l == 1) ? 75   : (l == 2) ? 38   : 19;
            const int   H  = (l == 0) ? 100   : (l == 1) ? 50   : (l == 2) ? 25   : 13;
            const int   S  = (l == 0) ? 0     : (l == 1) ? 15000: (l == 2) ? 18750: 19700;

            const float x = xy.x * fW - 0.5f;
            const float y = xy.y * fH - 0.5f;
            const float x0f = floorf(x);
            const float y0f = floorf(y);
            const float wx1 = x - x0f;
            const float wy1 = y - y0f;
            const float wx0 = 1.f - wx1;
            const float wy0 = 1.f - wy1;
            const int x0 = (int)x0f, y0 = (int)y0f;   // in [-1, W-1]
            const int x1 = x0 + 1,   y1 = y0 + 1;     // in [0, W]

            const float wx0m = ((unsigned)x0 < (unsigned)W) ? wx0 : 0.f;
            const float wx1m = ((unsigned)x1 < (unsigned)W) ? wx1 : 0.f;
            const float wy0m = ((unsigned)y0 < (unsigned)H) ? aw * wy0 : 0.f;
            const float wy1m = ((unsigned)y1 < (unsigned)H) ? aw * wy1 : 0.f;
            const float c00 = wy0m * wx0m;
            const float c01 = wy0m * wx1m;
            const float c10 = wy1m * wx0m;
            const float c11 = wy1m * wx1m;

            const int cx0 = max(x0, 0), cx1 = min(x1, W - 1);
            const int cy0 = max(y0, 0), cy1 = min(y1, H - 1);
            const bool xi = cx1 > cx0;     // slot1 really is corner x1
            const int rb0 = S + cy0 * W + cx0;   // paired row index, y0
            const int rb1 = S + cy1 * W + cx0;   // paired row index, y1

            float* m = &s_meta[pair * PSTR + sp * 8];
            f32x4 e0, e1;
            e0.x = xi ? c00 : (c00 + c01);
            e0.y = xi ? c10 : (c10 + c11);
            e0.z = __int_as_float(rb0);
            e0.w = __int_as_float(rb1);
            e1.x = xi ? c01 : 0.f;
            e1.y = xi ? c11 : 0.f;
            e1.z = __int_as_float(rb0);
            e1.w = __int_as_float(rb1);
            *(f32x4*)(m)     = e0;         // slot 0 entry
            *(f32x4*)(m + 4) = e1;         // slot 1 entry
        }
    }
    __syncthreads();

    // ---- phase 2: load ALL 16 rows first, then FMA pass ----
    const int pair = t >> 4;
    const int lane = t & 15;
    const int g    = lane & 3;            // ch group (8 ch)
    const int s    = (lane >> 2) & 1;     // token slot (x corner)
    const int half = lane >> 3;           // sample half: 0 -> sp 0-7, 1 -> 8-15
    const int q    = q0 + pair;
    if (q >= NQ) return;

    const float* mbase = &s_meta[pair * PSTR + (half * 8) * 8 + s * 4];
    const _Float16* vf = ws + (size_t)h * HSTR2 + g * 16 + s * 8;

    // phase 2a: issue all 16 corner loads (no FMAs interleaved)
    f16x8 ga[8], gb[8];
#pragma unroll
    for (int u = 0; u < 8; ++u) {
        const int rb0 = __float_as_int(mbase[u * 8 + 2]);
        const int rb1 = __float_as_int(mbase[u * 8 + 3]);
        ga[u] = *(const f16x8*)(vf + (size_t)rb0 * 64);
        gb[u] = *(const f16x8*)(vf + (size_t)rb1 * 64);
    }

    // phase 2b: FMA pass (coefs re-read from LDS while loads drain)
    f32x8 acc = {0.f, 0.f, 0.f, 0.f, 0.f, 0.f, 0.f, 0.f};
#pragma unroll
    for (int u = 0; u < 8; ++u) {
        const float fA = mbase[u * 8 + 0];
        const float fB = mbase[u * 8 + 1];
#pragma unroll
        for (int k = 0; k < 8; ++k) {
            acc[k] += fA * (float)ga[u][k];
            acc[k] += fB * (float)gb[u][k];
        }
    }

    // combine slots (xor 4) then halves (xor 8)
#pragma unroll
    for (int k = 0; k < 8; ++k) acc[k] += __shfl_xor(acc[k], 4);
#pragma unroll
    for (int k = 0; k < 8; ++k) acc[k] += __shfl_xor(acc[k], 8);

    if (s == 0) {   // 8 lanes (half,g) x 16 B = contiguous 128 B per pair
        float* op = out + (size_t)(q * HEADS + h) * DCH + g * 8 + half * 4;
        const f32x4 part = half ? f32x4{acc[4], acc[5], acc[6], acc[7]}
                                : f32x4{acc[0], acc[1], acc[2], acc[3]};
        __builtin_nontemporal_store(part, (f32x4*)op);
    }
}

// ---- fp32 direct fallback (correctness only, tiny ws) ----------------------
__global__ __launch_bounds__(256)
void msda_f32_kernel(const float* __restrict__ value,
                     const float* __restrict__ loc,
                     const float* __restrict__ attw,
                     float* __restrict__ out)
{
    const int t    = blockIdx.x * blockDim.x + threadIdx.x;
    const int pair = t >> 3;
    const int d0   = (t & 7) * 4;
    if (pair >= NQ * HEADS) return;
    const int h = pair & 7;

    const float* locp = loc  + (size_t)pair * (NSP * 2);
    const float* awp  = attw + (size_t)pair * NSP;
    f32x4 acc = {0.f, 0.f, 0.f, 0.f};

#pragma unroll
    for (int sp = 0; sp < NSP; ++sp) {
        const int l = sp >> 2;
        const int W = (l == 0) ? 150 : (l == 1) ? 75 : (l == 2) ? 38 : 19;
        const int H = (l == 0) ? 100 : (l == 1) ? 50 : (l == 2) ? 25 : 13;
        const int S = (l == 0) ? 0 : (l == 1) ? 15000 : (l == 2) ? 18750 : 19700;
        const float x = locp[sp * 2] * W - 0.5f;
        const float y = locp[sp * 2 + 1] * H - 0.5f;
        const float aw = awp[sp];
        const float x0f = floorf(x), y0f = floorf(y);
        const float wx1 = x - x0f, wy1 = y - y0f;
        const float wx0 = 1.f - wx1, wy0 = 1.f - wy1;
        const int x0 = (int)x0f, y0 = (int)y0f, x1 = x0 + 1, y1 = y0 + 1;
        const float wx0m = ((unsigned)x0 < (unsigned)W) ? wx0 : 0.f;
        const float wx1m = ((unsigned)x1 < (unsigned)W) ? wx1 : 0.f;
        const float wy0m = ((unsigned)y0 < (unsigned)H) ? aw * wy0 : 0.f;
        const float wy1m = ((unsigned)y1 < (unsigned)H) ? aw * wy1 : 0.f;
        const int cx0 = max(x0, 0), cx1 = min(x1, W - 1);
        const int cy0 = max(y0, 0), cy1 = min(y1, H - 1);
        const size_t r0 = (size_t)(S + cy0 * W), r1 = (size_t)(S + cy1 * W);
        const f32x4 g00 = *(const f32x4*)(value + ((r0 + cx0) * 8 + h) * DCH + d0);
        const f32x4 g01 = *(const f32x4*)(value + ((r0 + cx1) * 8 + h) * DCH + d0);
        const f32x4 g10 = *(const f32x4*)(value + ((r1 + cx0) * 8 + h) * DCH + d0);
        const f32x4 g11 = *(const f32x4*)(value + ((r1 + cx1) * 8 + h) * DCH + d0);
        acc += g00 * (wy0m * wx0m);
        acc += g01 * (wy0m * wx1m);
        acc += g10 * (wy1m * wx0m);
        acc += g11 * (wy1m * wx1m);
    }
    *(f32x4*)(out + (size_t)pair * DCH + d0) = acc;
}

extern "C" void kernel_launch(void* const* d_in, const int* in_sizes, int n_in,
                              void* d_out, int out_size, void* d_ws, size_t ws_size,
                              hipStream_t stream) {
    const float* value = (const float*)d_in[0];
    const float* loc   = (const float*)d_in[3];
    const float* attw  = (const float*)d_in[4];
    float* out = (float*)d_out;

    const size_t pair_bytes = (size_t)NQ * HEADS * 64 * sizeof(_Float16); // 20.4 MB

    if (ws_size >= pair_bytes) {
        _Float16* ws = (_Float16*)d_ws;
        const int cgrid = ((NQ * 4 + 255) / 256) * HEADS;                 // XCD-aligned
        cvt_pair_kernel<<<cgrid, 256, 0, stream>>>(value, ws);
        const int qblocks = (NQ + 15) / 16;                               // 1247
        msda_meta_kernel<<<qblocks * HEADS, 256, 0, stream>>>(ws, loc, attw, out);
    } else {
        const int total = NQ * HEADS * 8;
        msda_f32_kernel<<<(total + 255) / 256, 256, 0, stream>>>(value, loc, attw, out);
    }
}